// Round 1
// baseline (149.442 us; speedup 1.0000x reference)
//
#include <hip/hip_runtime.h>

// FSAF target assignment, MI355X.
// Output layout (f32, concatenated): cls_t (16,21824,80) | cls_m (16,21824) |
// num_pos (16,) | reg_t (16,21824,4) | reg_m (16,21824)

#define NPIX      21824
#define NBOX      64
#define BATCH     16
#define NUM_CLS   80
#define BIG_AREA  10000000.0f

#define CLSM_OFF  27934720          // 16*21824*80
#define NUMP_OFF  28283904          // CLSM_OFF + 16*21824
#define REGT_OFF  28283920          // NUMP_OFF + 16
#define REGM_OFF  29680656          // REGT_OFF + 16*21824*4
// REGT_OFF/4 = 7070980  (float4-aligned)

__device__ __forceinline__ void prop_box(float x1, float y1, float x2, float y2,
                                         float a, float fwf, float fhf,
                                         int& ox1, int& oy1, int& ox2, int& oy2) {
    // Match numpy exactly: no FMA contraction (use _rn intrinsics).
    float w = __fsub_rn(x2, x1);
    float h = __fsub_rn(y2, y1);
    float nx1 = floorf(__fadd_rn(x1, __fmul_rn(a, w)));
    float ny1 = floorf(__fadd_rn(y1, __fmul_rn(a, h)));
    float nx2 = ceilf(__fsub_rn(x2, __fmul_rn(a, w)));
    float ny2 = ceilf(__fsub_rn(y2, __fmul_rn(a, h)));
    nx2 = fminf(fmaxf(fmaxf(nx2, __fadd_rn(nx1, 1.0f)), 0.0f), fwf);
    ny2 = fminf(fmaxf(fmaxf(ny2, __fadd_rn(ny1, 1.0f)), 0.0f), fhf);
    nx1 = fminf(fmaxf(nx1, 0.0f), fwf - 1.0f);
    ny1 = fminf(fmaxf(ny1, 0.0f), fhf - 1.0f);
    ox1 = (int)nx1; oy1 = (int)ny1; ox2 = (int)nx2; oy2 = (int)ny2;
}

__global__ __launch_bounds__(256) void fsaf_kernel(const int* __restrict__ levels,
                                                   const float* __restrict__ gt,
                                                   float* __restrict__ out) {
    const int img = blockIdx.y;
    const int bx  = blockIdx.x;          // 0..85 — each block inside one level
    const int tid = threadIdx.x;

    int level, loff, fwl;
    if      (bx < 64) { level = 0; loff = 0;     fwl = 7; }   // 128x128
    else if (bx < 80) { level = 1; loff = 16384; fwl = 6; }   // 64x64
    else if (bx < 84) { level = 2; loff = 20480; fwl = 5; }   // 32x32
    else if (bx == 84){ level = 3; loff = 21504; fwl = 4; }   // 16x16
    else              { level = 4; loff = 21760; fwl = 3; }   // 8x8 (64 px)

    const int   fw      = 1 << fwl;
    const float stride  = (float)(8 << level);
    const int   pixBase = bx << 8;                 // within-image pixel offset
    const int   numPix  = min(256, NPIX - pixBase);

    __shared__ int   s_px1[NBOX], s_py1[NBOX], s_px2[NBOX], s_py2[NBOX];
    __shared__ int   s_ix1[NBOX], s_iy1[NBOX], s_ix2[NBOX], s_iy2[NBOX];
    __shared__ float s_area[NBOX];
    __shared__ float s_bx1[NBOX], s_by1[NBOX], s_bx2[NBOX], s_by2[NBOX];
    __shared__ int   s_lab[NBOX];
    __shared__ int   s_plab[256];                  // chosen label per pixel, -1 if not pos

    if (tid < NBOX) {
        const int n = tid;
        const float* g = gt + (size_t)(img * NBOX + n) * 5;
        float bx1 = g[0], by1 = g[1], bx2 = g[2], by2 = g[3];
        int   lab = (int)g[4];
        bool  valid = (levels[img * NBOX + n] == level);

        s_bx1[n] = bx1; s_by1[n] = by1; s_bx2[n] = bx2; s_by2[n] = by2;
        s_lab[n] = lab;
        // area in image coords (single sub/sub/mul — no contraction risk)
        s_area[n] = (bx2 - bx1) * (by2 - by1);

        const float inv = 1.0f / stride;           // stride is pow2 -> exact
        float px1 = bx1 * inv, py1 = by1 * inv, px2 = bx2 * inv, py2 = by2 * inv;
        const float fwf = (float)fw, fhf = (float)fw;

        int a1, b1, a2, b2;
        prop_box(px1, py1, px2, py2, 0.4f, fwf, fhf, a1, b1, a2, b2);   // POS_SCALE=0.2
        if (!valid) { a2 = -1; }                   // empty region
        s_px1[n] = a1; s_py1[n] = b1; s_px2[n] = a2; s_py2[n] = b2;

        prop_box(px1, py1, px2, py2, 0.25f, fwf, fhf, a1, b1, a2, b2);  // IGNORE_SCALE=0.5
        if (!valid) { a2 = -1; }
        s_ix1[n] = a1; s_iy1[n] = b1; s_ix2[n] = a2; s_iy2[n] = b2;
    }
    __syncthreads();

    const int  p      = pixBase + tid;             // within-image pixel index
    const bool active = tid < numPix;

    float best   = BIG_AREA;
    int   chosen = 0;
    bool  anyIgn = false;

    int x = 0, y = 0;
    if (active) {
        int local = p - loff;
        y = local >> fwl;
        x = local & (fw - 1);
        #pragma unroll 8
        for (int n = 0; n < NBOX; ++n) {
            bool inp = (y >= s_py1[n]) & (y < s_py2[n]) & (x >= s_px1[n]) & (x < s_px2[n]);
            bool ing = (y >= s_iy1[n]) & (y < s_iy2[n]) & (x >= s_ix1[n]) & (x < s_ix2[n]);
            anyIgn |= ing;
            float am = inp ? s_area[n] : BIG_AREA;
            bool better = am < best;               // strict '<' => first-min, matches argmin
            best   = better ? am : best;
            chosen = better ? n  : chosen;
        }
    }
    const bool anyPos = best < BIG_AREA;

    const size_t imgBase = (size_t)img * NPIX;
    if (active) {
        out[CLSM_OFF + imgBase + p] = (anyPos || !anyIgn) ? 1.0f : 0.0f;
        out[REGM_OFF + imgBase + p] = anyPos ? 1.0f : 0.0f;

        float4 rt = {0.f, 0.f, 0.f, 0.f};
        if (anyPos) {
            float sx = ((float)x + 0.5f) * stride;   // exact
            float sy = ((float)y + 0.5f) * stride;
            rt.x = (sx - s_bx1[chosen]) * 0.25f;     // sub then *0.25 (exact scale)
            rt.y = (sy - s_by1[chosen]) * 0.25f;
            rt.z = (s_bx2[chosen] - sx) * 0.25f;
            rt.w = (s_by2[chosen] - sy) * 0.25f;
        }
        ((float4*)out)[(size_t)REGT_OFF / 4 + imgBase + p] = rt;
    }
    s_plab[tid] = (active && anyPos) ? s_lab[chosen] : -1;

    // num_pos: per-wave ballot + one float atomic per wave
    unsigned long long bal = __ballot(active && anyPos);
    if ((tid & 63) == 0) {
        int c = __popcll(bal);
        if (c) atomicAdd(out + NUMP_OFF + img, (float)c);
    }
    __syncthreads();

    // cls_target: cooperative, fully-coalesced float4 one-hot write.
    // 20 float4 per pixel (80 classes).
    float4* cls4 = (float4*)out;
    const size_t base4 = (imgBase + (size_t)pixBase) * 20;
    const int total4 = numPix * 20;
    for (int f = tid; f < total4; f += 256) {
        int pix = f / 20;
        int c4  = f - pix * 20;
        int rel = s_plab[pix] - c4 * 4;
        float4 v = {0.f, 0.f, 0.f, 0.f};
        if      (rel == 0) v.x = 1.0f;
        else if (rel == 1) v.y = 1.0f;
        else if (rel == 2) v.z = 1.0f;
        else if (rel == 3) v.w = 1.0f;
        cls4[base4 + f] = v;
    }
}

extern "C" void kernel_launch(void* const* d_in, const int* in_sizes, int n_in,
                              void* d_out, int out_size, void* d_ws, size_t ws_size,
                              hipStream_t stream) {
    const int*   levels = (const int*)d_in[0];    // (16,64) int32
    const float* gt     = (const float*)d_in[1];  // (16,64,5) f32
    float*       out    = (float*)d_out;

    // zero num_pos accumulators (graph-capture-safe)
    hipMemsetAsync((char*)d_out + (size_t)NUMP_OFF * sizeof(float), 0,
                   BATCH * sizeof(float), stream);

    dim3 grid(86, BATCH);
    fsaf_kernel<<<grid, 256, 0, stream>>>(levels, gt, out);
}

// Round 2
// 140.254 us; speedup vs baseline: 1.0655x; 1.0655x over previous
//
#include <hip/hip_runtime.h>

// FSAF target assignment, MI355X.
// Output layout (f32, concatenated): cls_t (16,21824,80) | cls_m (16,21824) |
// num_pos (16,) | reg_t (16,21824,4) | reg_m (16,21824)

#define NPIX      21824
#define NBOX      64
#define BATCH     16
#define BIG_AREA  10000000.0f

#define CLSM_OFF  27934720          // 16*21824*80
#define NUMP_OFF  28283904          // CLSM_OFF + 16*21824
#define REGT_OFF  28283920          // NUMP_OFF + 16
#define REGM_OFF  29680656          // REGT_OFF + 16*21824*4
// REGT_OFF/4 = 7070980  (float4-aligned)

__device__ __forceinline__ void prop_box(float x1, float y1, float x2, float y2,
                                         float a, float fwf,
                                         int& ox1, int& oy1, int& ox2, int& oy2) {
    // Match numpy exactly: block FMA contraction with _rn intrinsics.
    float w = __fsub_rn(x2, x1);
    float h = __fsub_rn(y2, y1);
    float nx1 = floorf(__fadd_rn(x1, __fmul_rn(a, w)));
    float ny1 = floorf(__fadd_rn(y1, __fmul_rn(a, h)));
    float nx2 = ceilf(__fsub_rn(x2, __fmul_rn(a, w)));
    float ny2 = ceilf(__fsub_rn(y2, __fmul_rn(a, h)));
    nx2 = fminf(fmaxf(fmaxf(nx2, __fadd_rn(nx1, 1.0f)), 0.0f), fwf);
    ny2 = fminf(fmaxf(fmaxf(ny2, __fadd_rn(ny1, 1.0f)), 0.0f), fwf);
    nx1 = fminf(fmaxf(nx1, 0.0f), fwf - 1.0f);
    ny1 = fminf(fmaxf(ny1, 0.0f), fwf - 1.0f);
    ox1 = (int)nx1; oy1 = (int)ny1; ox2 = (int)nx2; oy2 = (int)ny2;
}

__global__ __launch_bounds__(256) void fsaf_kernel(const int* __restrict__ levels,
                                                   const float* __restrict__ gt,
                                                   float* __restrict__ out) {
    const int img = blockIdx.y;
    const int bx  = blockIdx.x;          // 0..85 — each block inside one level
    const int tid = threadIdx.x;

    int level, loff, fwl;
    if      (bx < 64) { level = 0; loff = 0;     fwl = 7; }   // 128x128
    else if (bx < 80) { level = 1; loff = 16384; fwl = 6; }   // 64x64
    else if (bx < 84) { level = 2; loff = 20480; fwl = 5; }   // 32x32
    else if (bx == 84){ level = 3; loff = 21504; fwl = 4; }   // 16x16
    else              { level = 4; loff = 21760; fwl = 3; }   // 8x8 (64 px)

    const int    fw      = 1 << fwl;
    const float  stride  = (float)(8 << level);
    const int    pixBase = bx << 8;
    const int    numPix  = min(256, NPIX - pixBase);
    const size_t imgBase = (size_t)img * NPIX;

    // ---- 1. cls_target zero-fill: pure coalesced dwordx4 stream, no LDS dep.
    float4* cls4 = (float4*)out;
    const size_t base4  = (imgBase + (size_t)pixBase) * 20;
    const int    total4 = numPix * 20;
    const float4 z4 = {0.f, 0.f, 0.f, 0.f};
    for (int f = tid; f < total4; f += 256) cls4[base4 + f] = z4;

    // ---- 2. wave-0: per-box prop rects + tile-row intersection compaction.
    __shared__ int4   s_pos[NBOX];     // compacted pos rect (x1,y1,x2,y2)
    __shared__ int4   s_ign[NBOX];     // compacted ignore rect (superset of pos)
    __shared__ float  s_area[NBOX];
    __shared__ float4 s_box[NBOX];     // image-coord box for regr target
    __shared__ int    s_lab[NBOX];
    __shared__ int    s_cnt;

    if (tid < NBOX) {
        const float* g = gt + (size_t)(img * NBOX + tid) * 5;
        float b0 = g[0], b1 = g[1], b2 = g[2], b3 = g[3];
        int   lab   = (int)g[4];
        bool  valid = (levels[img * NBOX + tid] == level);

        const float inv = 1.0f / stride;              // pow2 -> exact
        float px1 = b0 * inv, py1 = b1 * inv, px2 = b2 * inv, py2 = b3 * inv;
        const float fwf = (float)fw;

        int pa, pb, pc, pd, ia, ib, ic, id;
        prop_box(px1, py1, px2, py2, 0.4f,  fwf, pa, pb, pc, pd);  // POS_SCALE=0.2
        prop_box(px1, py1, px2, py2, 0.25f, fwf, ia, ib, ic, id);  // IGNORE_SCALE=0.5

        // tile = full-width rows [y0, yEnd); ignore-rect row test (pos ⊆ ign)
        int y0   = (pixBase - loff) >> fwl;
        int yEnd = y0 + (numPix >> fwl);
        bool hit = valid && (ib < yEnd) && (id > y0);

        unsigned long long m = __ballot(hit);         // wave 0 only
        if (hit) {
            int idx = __popcll(m & ((1ull << tid) - 1ull));  // order-preserving
            s_pos[idx]  = make_int4(pa, pb, pc, pd);
            s_ign[idx]  = make_int4(ia, ib, ic, id);
            s_area[idx] = (b2 - b0) * (b3 - b1);      // sub,sub,mul — no FMA risk
            s_box[idx]  = make_float4(b0, b1, b2, b3);
            s_lab[idx]  = lab;
        }
        if (tid == 0) s_cnt = __popcll(m);
    }
    __syncthreads();

    // ---- 3. per-pixel scan over the (short) compacted list.
    const int  p      = pixBase + tid;
    const bool active = tid < numPix;
    const int  local  = p - loff;
    const int  y      = local >> fwl;
    const int  x      = local & (fw - 1);

    float best   = BIG_AREA;
    int   chosen = 0;
    bool  anyIgn = false;
    const int cnt = s_cnt;
    for (int n = 0; n < cnt; ++n) {
        int4 ig = s_ign[n];
        bool ing = (y >= ig.y) & (y < ig.w) & (x >= ig.x) & (x < ig.z);
        anyIgn |= ing;
        int4 ps = s_pos[n];
        bool inp = (y >= ps.y) & (y < ps.w) & (x >= ps.x) & (x < ps.z);
        float am = inp ? s_area[n] : BIG_AREA;
        bool better = am < best;                      // strict '<' = first-min
        best   = better ? am : best;
        chosen = better ? n  : chosen;
    }
    const bool anyPos = best < BIG_AREA;

    if (active) {
        out[CLSM_OFF + imgBase + p] = (anyPos || !anyIgn) ? 1.0f : 0.0f;
        out[REGM_OFF + imgBase + p] = anyPos ? 1.0f : 0.0f;

        float4 rt = z4;
        if (anyPos) {
            float4 cb = s_box[chosen];
            float sx = ((float)x + 0.5f) * stride;    // exact
            float sy = ((float)y + 0.5f) * stride;
            rt.x = (sx - cb.x) * 0.25f;
            rt.y = (sy - cb.y) * 0.25f;
            rt.z = (cb.z - sx) * 0.25f;
            rt.w = (cb.w - sy) * 0.25f;
            // sparse one-hot scatter; zero-fill above is ordered by the barrier
            out[(imgBase + p) * 80 + s_lab[chosen]] = 1.0f;
        }
        ((float4*)out)[(size_t)REGT_OFF / 4 + imgBase + p] = rt;
    }

    // ---- 4. num_pos: per-wave ballot + one float atomic per wave.
    unsigned long long bal = __ballot(active && anyPos);
    if ((tid & 63) == 0) {
        int c = __popcll(bal);
        if (c) atomicAdd(out + NUMP_OFF + img, (float)c);
    }
}

extern "C" void kernel_launch(void* const* d_in, const int* in_sizes, int n_in,
                              void* d_out, int out_size, void* d_ws, size_t ws_size,
                              hipStream_t stream) {
    const int*   levels = (const int*)d_in[0];    // (16,64) int32
    const float* gt     = (const float*)d_in[1];  // (16,64,5) f32
    float*       out    = (float*)d_out;

    // zero the 16 num_pos accumulators (graph-capture-safe)
    hipMemsetAsync((char*)d_out + (size_t)NUMP_OFF * sizeof(float), 0,
                   BATCH * sizeof(float), stream);

    dim3 grid(86, BATCH);
    fsaf_kernel<<<grid, 256, 0, stream>>>(levels, gt, out);
}